// Round 8
// baseline (364.362 us; speedup 1.0000x reference)
//
#include <hip/hip_runtime.h>

// Problem constants
#define DIMV   512
#define NEMB   4096
#define NTOK   32768                 // B*H*W
#define TOTAL  (NTOK * DIMV)         // 16,777,216

// Output layout (flat f32, concatenated in return order)
#define OFF_Q    0u
#define OFF_DIFF 16777216u
#define OFF_IND  16777217u
#define OFF_NE   16809985u
#define OFF_NCS  18907137u
#define OFF_NEA  18911233u

// ws layout (float-element offsets)
#define WS_SUMT    0u          // float [NEMB][DIMV]  (8 MB), fully overwritten
#define WS_BINCNT  2097152u    // int[4096]
#define WS_BINST   2101248u    // int[4096]
#define WS_CURSOR  2105344u    // int[4096]
#define WS_SORTED  2109440u    // int[32768]
#define WS_DIFF    2142208u    // float
#define WS_NSUM    2142209u    // float

#define DECAYF 0.99f
#define OMDF   0.01f
#define EPSF   1e-5f

// ---------------------------------------------------------------------------
// Histogram + embed_ind. 128 blocks x 256.
__global__ void k_hist(const int* __restrict__ labels,
                       float* __restrict__ out,
                       int* __restrict__ bin_count) {
    int n = blockIdx.x * 256 + threadIdx.x;
    int lab = labels[n];
    out[OFF_IND + n] = (float)lab;
    atomicAdd(&bin_count[lab], 1);
}

// ---------------------------------------------------------------------------
// Scan over 4096 bins + ncs + n_sum + cursor init + diff_acc zero. 1 block.
__global__ void k_scan(const int* __restrict__ bin_count,
                       const float* __restrict__ cluster_size,
                       int* __restrict__ bin_start,
                       int* __restrict__ cursor,
                       float* __restrict__ out,
                       float* __restrict__ n_sum,
                       float* __restrict__ diff_acc) {
    __shared__ int   part[256];
    __shared__ float fred[256];
    int t = threadIdx.x;
    int base = t * 16;
    int loc[16];
    int s = 0; float nl = 0.f;
    #pragma unroll
    for (int i = 0; i < 16; ++i) {
        int cc = bin_count[base + i];
        loc[i] = s; s += cc;
        float ncs = cluster_size[base + i] * DECAYF + OMDF * (float)cc;
        out[OFF_NCS + base + i] = ncs;
        nl += ncs;
    }
    part[t] = s;
    fred[t] = nl;
    __syncthreads();
    for (int o = 1; o < 256; o <<= 1) {
        int v = (t >= o) ? part[t - o] : 0;
        __syncthreads();
        part[t] += v;
        __syncthreads();
    }
    for (int o = 128; o > 0; o >>= 1) {
        if (t < o) fred[t] += fred[t + o];
        __syncthreads();
    }
    if (t == 0) { n_sum[0] = fred[0]; diff_acc[0] = 0.f; }
    int off = (t == 0) ? 0 : part[t - 1];
    #pragma unroll
    for (int i = 0; i < 16; ++i) {
        bin_start[base + i] = off + loc[i];
        cursor[base + i]    = off + loc[i];
    }
}

// ---------------------------------------------------------------------------
// Counting-sort scatter. 128 blocks x 256.
__global__ void k_scatter(const int* __restrict__ labels,
                          int* __restrict__ cursor,
                          int* __restrict__ sorted_tok) {
    int n = blockIdx.x * 256 + threadIdx.x;
    int lab = labels[n];
    int pos = atomicAdd(&cursor[lab], 1);
    sorted_tok[pos] = n;
}

// ---------------------------------------------------------------------------
// WAVE = (label, 128-dim group). 4096 blocks x 4 waves = 16384 waves.
// Lane owns 2 dims (float2). 8-deep batched load pipeline, no LDS, no
// syncs, no atomics (except 1 diff atomic per wave).
__global__ __launch_bounds__(256) void k_perlabel(
        const float* __restrict__ inp,
        const float* __restrict__ embed,
        const int*   __restrict__ sorted_tok,
        const int*   __restrict__ bin_start,
        const int*   __restrict__ bin_count,
        float* __restrict__ out,
        float* __restrict__ sumT,
        float* __restrict__ diff_acc) {
    int t    = threadIdx.x;
    int g    = t >> 6;                     // dim-group 0..3 (= wave id)
    int lane = t & 63;
    int e    = blockIdx.x;                 // label
    int d0   = (g << 7) | (lane << 1);     // 2 dims per lane

    // embed column e, this wave's 2 dims (2 scalar stride-NEMB loads)
    float2 q;
    q.x = embed[(size_t)(d0 + 0) * NEMB + e];
    q.y = embed[(size_t)(d0 + 1) * NEMB + e];

    int start = bin_start[e];
    int cnt   = bin_count[e];

    float2 s2 = make_float2(0.f, 0.f);
    float dacc = 0.f;

    for (int base = 0; base < cnt; base += 64) {
        int m = min(64, cnt - base);
        int idx = (lane < m) ? sorted_tok[start + base + lane] : 0;
        for (int sub = 0; sub < m; sub += 8) {
            int mm = min(8, m - sub);
            int n[8];
            float2 x[8];
            // issue all loads for this sub-batch first
            #pragma unroll
            for (int j = 0; j < 8; ++j) {
                if (j < mm) {
                    n[j] = __shfl(idx, sub + j);
                    x[j] = *(const float2*)(inp + (size_t)n[j] * DIMV + d0);
                }
            }
            // consume
            #pragma unroll
            for (int j = 0; j < 8; ++j) {
                if (j < mm) {
                    s2.x += x[j].x; s2.y += x[j].y;
                    float t0 = q.x - x[j].x, t1 = q.y - x[j].y;
                    dacc += t0 * t0 + t1 * t1;
                    *(float2*)(out + OFF_Q + (size_t)n[j] * DIMV + d0) = q;
                }
            }
        }
    }

    // segment-sum slice for (e, dim-group): coalesced 512 B per wave
    *(float2*)(sumT + (size_t)e * DIMV + d0) = s2;

    // diff: wave shuffle-reduce -> one atomic per wave
    for (int o = 32; o > 0; o >>= 1) dacc += __shfl_down(dacc, o);
    if (lane == 0) atomicAdd(diff_acc, dacc);
}

// ---------------------------------------------------------------------------
// Tiled transpose of sumT [e][d] + EMA + normalize + diff finalize.
__global__ __launch_bounds__(256) void k_trans_final(
        const float* __restrict__ embed_avg,
        const float* __restrict__ sumT,
        const float* __restrict__ n_sum,
        const float* __restrict__ diff_acc,
        float* __restrict__ out) {
    __shared__ float tile[32][33];
    int tx = threadIdx.x & 31;
    int ty = threadIdx.x >> 5;
    int e0 = (blockIdx.x & 127) << 5;
    int d0 = (blockIdx.x >> 7) << 5;
    for (int i = 0; i < 4; ++i) {
        int er = ty + i * 8;
        tile[er][tx] = sumT[(size_t)(e0 + er) * DIMV + d0 + tx];
    }
    __syncthreads();
    float nsum = n_sum[0];
    float ncs  = out[OFF_NCS + e0 + tx];
    float cs   = (ncs + EPSF) / (nsum + (float)NEMB * EPSF) * nsum;
    float inv  = 1.0f / cs;
    for (int i = 0; i < 4; ++i) {
        int dr = d0 + ty + i * 8;
        size_t o = (size_t)dr * NEMB + e0 + tx;
        float val = DECAYF * embed_avg[o] + OMDF * tile[tx][ty + i * 8];
        out[OFF_NEA + o] = val;
        out[OFF_NE + o]  = val * inv;
    }
    if (blockIdx.x == 0 && threadIdx.x == 0)
        out[OFF_DIFF] = diff_acc[0] * (1.0f / (float)TOTAL);
}

// ---------------------------------------------------------------------------
extern "C" void kernel_launch(void* const* d_in, const int* in_sizes, int n_in,
                              void* d_out, int out_size, void* d_ws, size_t ws_size,
                              hipStream_t stream) {
    const float* inp          = (const float*)d_in[0];
    const int*   labels       = (const int*)  d_in[1];
    const float* embed        = (const float*)d_in[2];
    const float* cluster_size = (const float*)d_in[3];
    const float* embed_avg    = (const float*)d_in[4];
    float* out = (float*)d_out;

    float* wsf        = (float*)d_ws;
    float* sumT       = wsf + WS_SUMT;
    int*   bin_count  = (int*)(wsf + WS_BINCNT);
    int*   bin_start  = (int*)(wsf + WS_BINST);
    int*   cursor     = (int*)(wsf + WS_CURSOR);
    int*   sorted_tok = (int*)(wsf + WS_SORTED);
    float* diff_acc   = wsf + WS_DIFF;
    float* n_sum      = wsf + WS_NSUM;

    hipMemsetAsync(bin_count, 0, NEMB * sizeof(int), stream);
    k_hist      <<<128,  256, 0, stream>>>(labels, out, bin_count);
    k_scan      <<<1,    256, 0, stream>>>(bin_count, cluster_size, bin_start,
                                           cursor, out, n_sum, diff_acc);
    k_scatter   <<<128,  256, 0, stream>>>(labels, cursor, sorted_tok);
    k_perlabel  <<<4096, 256, 0, stream>>>(inp, embed, sorted_tok, bin_start,
                                           bin_count, out, sumT, diff_acc);
    k_trans_final<<<2048,256, 0, stream>>>(embed_avg, sumT, n_sum, diff_acc, out);
}